// Round 8
// baseline (377.010 us; speedup 1.0000x reference)
//
#include <hip/hip_runtime.h>
#include <hip/hip_bf16.h>

typedef __attribute__((ext_vector_type(8))) short short8;
typedef __attribute__((ext_vector_type(4))) float floatx4;

#define REG_CAP 106496   // per-shard pair-region capacity (~100K expected + slack)

__device__ __forceinline__ float bf_lo(unsigned int u) { return __uint_as_float(u << 16); }
__device__ __forceinline__ float bf_hi(unsigned int u) { return __uint_as_float(u & 0xffff0000u); }

__device__ __forceinline__ unsigned short f2bf_rne(float f) {
    unsigned u = __float_as_uint(f);
    unsigned rb = (u >> 16) & 1u;
    u += 0x7fffu + rb;
    return (unsigned short)(u >> 16);
}
__device__ __forceinline__ unsigned int pack_bf2(float x, float y) {
    return (unsigned int)f2bf_rne(x) | ((unsigned int)f2bf_rne(y) << 16);
}

// ---------------- fp32 -> bf16 converts ----------------

__global__ __launch_bounds__(256) void convert_pairs_kernel(const float* __restrict__ x,
                                                            unsigned int* __restrict__ xb, int total) {
    int i = blockIdx.x * blockDim.x + threadIdx.x;
    if (i < total) {
        float2 f = ((const float2*)x)[i];
        xb[i] = pack_bf2(f.x, f.y);
    }
}

__global__ __launch_bounds__(256) void heads_pack_kernel(const float* __restrict__ Wp, const float* __restrict__ bp,
                                                         const float* __restrict__ Wc, const float* __restrict__ bc,
                                                         unsigned short* __restrict__ Whb, float* __restrict__ hbias) {
    int i = blockIdx.x * blockDim.x + threadIdx.x;
    if (i < 80 * 64) {
        int r = i >> 6, c = i & 63;
        float v = 0.f;
        if (r < 64) v = Wp[r * 64 + c];
        else if (r < 74) v = Wc[(r - 64) * 64 + c];
        Whb[i] = f2bf_rne(v);
    }
    if (i < 80) {
        float v = 0.f;
        if (i < 64) v = bp[i];
        else if (i < 74) v = bc[i - 64];
        hbias[i] = v;
    }
}

// ---------------- CSR build: bin pairs by shard, then shard-local count/scatter ----------------

__global__ void init_shard_cursors_kernel(int* __restrict__ shard_cur) {
    if (threadIdx.x < 8) shard_cur[threadIdx.x] = threadIdx.x * REG_CAP;
}

__global__ __launch_bounds__(256) void bin_edges_kernel(const int* __restrict__ src,
                                                        const int* __restrict__ dst,
                                                        int* __restrict__ shard_cur,
                                                        int2* __restrict__ pairs, int E, int nBins) {
    __shared__ int cnt[8];
    __shared__ int base[8];
    const int chunk = (E + nBins - 1) / nBins;
    const int lo = blockIdx.x * chunk;
    const int hi = min(lo + chunk, E);
    if (threadIdx.x < 8) cnt[threadIdx.x] = 0;
    __syncthreads();
    for (int e = lo + threadIdx.x; e < hi; e += 256)
        atomicAdd(&cnt[(dst[e] >> 8) & 7], 1);
    __syncthreads();
    if (threadIdx.x < 8) {
        base[threadIdx.x] = atomicAdd(&shard_cur[threadIdx.x], cnt[threadIdx.x]);
        cnt[threadIdx.x] = 0;
    }
    __syncthreads();
    for (int e = lo + threadIdx.x; e < hi; e += 256) {
        int d = dst[e];
        int s = (d >> 8) & 7;
        int pos = base[s] + atomicAdd(&cnt[s], 1);
        if (pos < (s + 1) * REG_CAP) pairs[pos] = make_int2(src[e], d);
    }
}

__global__ __launch_bounds__(256) void count_deg_binned_kernel(const int2* __restrict__ pairs,
                                                               const int* __restrict__ shard_cur,
                                                               int* __restrict__ deg, int nSub) {
    const int s   = blockIdx.x & 7;
    const int sub = blockIdx.x >> 3;
    const int cnt = shard_cur[s] - s * REG_CAP;
    const int per = (cnt + nSub - 1) / nSub;
    const int lo = s * REG_CAP + sub * per;
    const int hi = min(lo + per, s * REG_CAP + cnt);
    for (int i = lo + threadIdx.x; i < hi; i += 256)
        atomicAdd(&deg[pairs[i].y], 1);
}

__global__ __launch_bounds__(256) void scatter_binned_kernel(const int2* __restrict__ pairs,
                                                             const int* __restrict__ shard_cur,
                                                             int* __restrict__ cursor,
                                                             int* __restrict__ csr_src, int nSub) {
    const int s   = blockIdx.x & 7;
    const int sub = blockIdx.x >> 3;
    const int cnt = shard_cur[s] - s * REG_CAP;
    const int per = (cnt + nSub - 1) / nSub;
    const int lo = s * REG_CAP + sub * per;
    const int hi = min(lo + per, s * REG_CAP + cnt);
    for (int i = lo + threadIdx.x; i < hi; i += 256) {
        int2 pr = pairs[i];
        int pos = atomicAdd(&cursor[pr.y], 1);
        csr_src[pos] = pr.x;
    }
}

// Two-level scan, 256 elements per block.
__global__ __launch_bounds__(256) void partial_sum_kernel(const int* __restrict__ deg,
                                                          int* __restrict__ partial, int n) {
    __shared__ int s[256];
    int t = threadIdx.x;
    int i = blockIdx.x * 256 + t;
    s[t] = (i < n) ? deg[i] : 0;
    __syncthreads();
    for (int off = 128; off > 0; off >>= 1) {
        if (t < off) s[t] += s[t + off];
        __syncthreads();
    }
    if (t == 0) partial[blockIdx.x] = s[0];
}

__global__ __launch_bounds__(256) void scan_partials_kernel(const int* __restrict__ partial,
                                                            int* __restrict__ blockoff,
                                                            int* __restrict__ offsets,
                                                            int nblocks, int n) {
    __shared__ int s[256];
    int t = threadIdx.x;
    int v = (t < nblocks) ? partial[t] : 0;
    s[t] = v;
    __syncthreads();
    for (int off = 1; off < 256; off <<= 1) {
        int u = (t >= off) ? s[t - off] : 0;
        __syncthreads();
        s[t] += u;
        __syncthreads();
    }
    if (t < nblocks) blockoff[t] = s[t] - v;
    if (t == nblocks - 1) offsets[n] = s[t];
}

__global__ __launch_bounds__(256) void local_scan_kernel(const int* __restrict__ deg,
                                                         const int* __restrict__ blockoff,
                                                         int* __restrict__ offsets,
                                                         int* __restrict__ cursor, int n) {
    __shared__ int s[256];
    int t = threadIdx.x;
    int i = blockIdx.x * 256 + t;
    int v = (i < n) ? deg[i] : 0;
    s[t] = v;
    __syncthreads();
    for (int off = 1; off < 256; off <<= 1) {
        int u = (t >= off) ? s[t - off] : 0;
        __syncthreads();
        s[t] += u;
        __syncthreads();
    }
    if (i < n) {
        int o = blockoff[blockIdx.x] + s[t] - v;
        offsets[i] = o;
        cursor[i]  = o;
    }
}

// ---------------- Fused layer: mean-aggregate (LDS) -> MFMA GEMM -> (heads) ----------------
// 256 thr = 4 waves; 64 nodes/block. Stage 1: each wave aggregates 16 nodes
// (lanes = feature columns, neighbor indices broadcast via shfl), rows stored
// bf16 in LDS with padded stride (2-way bank conflicts only). Stage 2: MFMA
// 16x16x32 per wave, A from LDS, B (weights) from global (L1-resident).
// MODE 0: relu, bf16 out (next gather table). MODE 2: layer3+heads — relu,
// fp32 emb out + bf16 Y to LDS, barrier, heads MFMA (80 outs), nev/cls out.

template <int F_IN, int F_OUT, int MODE>
__global__ __launch_bounds__(256) void fused_layer_kernel(const unsigned int* __restrict__ xt,
                                                          const int* __restrict__ offsets,
                                                          const int* __restrict__ csr_src,
                                                          const unsigned short* __restrict__ Wb,
                                                          const float* __restrict__ bias,
                                                          unsigned int* __restrict__ Yb,
                                                          float* __restrict__ emb,
                                                          float* __restrict__ nev,
                                                          float* __restrict__ cls,
                                                          const unsigned short* __restrict__ Whb,
                                                          const float* __restrict__ hbias,
                                                          int n) {
    constexpr int STR = F_IN / 2 + 4;      // uint stride: 36 (F=64) / 68 (F=128)
    constexpr int KC  = F_IN / 32;
    constexpr int NJ  = F_OUT / 16;
    __shared__ unsigned int Atile[64 * STR];
    __shared__ unsigned int Ytile[(MODE == 2) ? 64 * 36 : 1];

    const int lane = threadIdx.x & 63;
    const int wv   = threadIdx.x >> 6;
    const int quad = lane >> 4;
    const int r16  = lane & 15;

    // ---- stage 1: aggregate 16 nodes per wave into LDS ----
    for (int t = 0; t < 16; ++t) {
        const int node = blockIdx.x * 64 + wv * 16 + t;
        const int lrow = wv * 16 + t;
        if (node >= n) {
            if (F_IN == 128) Atile[lrow * STR + lane] = 0;
            else if (lane < 32) Atile[lrow * STR + lane] = 0;
            continue;
        }
        const int start = offsets[node];
        const int end   = offsets[node + 1];

        if (F_IN == 64) {
            const int half = lane >> 5;
            const int col  = lane & 31;
            float s0 = 0.f, s1 = 0.f;
            int e = start;
            while (e < end) {
                int cnt = min(64, end - e);
                int ii = e + lane; if (ii >= end) ii = end - 1;
                int idx = csr_src[ii];
                int j = 0;
                for (; j + 8 <= cnt; j += 8) {
                    int a0 = __shfl(idx, j + 0, 64), a1 = __shfl(idx, j + 1, 64);
                    int a2 = __shfl(idx, j + 2, 64), a3 = __shfl(idx, j + 3, 64);
                    int a4 = __shfl(idx, j + 4, 64), a5 = __shfl(idx, j + 5, 64);
                    int a6 = __shfl(idx, j + 6, 64), a7 = __shfl(idx, j + 7, 64);
                    int n0 = half ? a1 : a0, n1 = half ? a3 : a2;
                    int n2 = half ? a5 : a4, n3 = half ? a7 : a6;
                    unsigned int u0 = xt[(size_t)n0 * 32 + col];
                    unsigned int u1 = xt[(size_t)n1 * 32 + col];
                    unsigned int u2 = xt[(size_t)n2 * 32 + col];
                    unsigned int u3 = xt[(size_t)n3 * 32 + col];
                    s0 += bf_lo(u0) + bf_lo(u1) + bf_lo(u2) + bf_lo(u3);
                    s1 += bf_hi(u0) + bf_hi(u1) + bf_hi(u2) + bf_hi(u3);
                }
                for (; j + 2 <= cnt; j += 2) {
                    int a0 = __shfl(idx, j, 64), a1 = __shfl(idx, j + 1, 64);
                    int nb = half ? a1 : a0;
                    unsigned int u = xt[(size_t)nb * 32 + col];
                    s0 += bf_lo(u); s1 += bf_hi(u);
                }
                if (j < cnt) {
                    int nb = __shfl(idx, j, 64);
                    if (!half) {
                        unsigned int u = xt[(size_t)nb * 32 + col];
                        s0 += bf_lo(u); s1 += bf_hi(u);
                    }
                }
                e += cnt;
            }
            s0 += __shfl(s0, lane ^ 32, 64);
            s1 += __shfl(s1, lane ^ 32, 64);
            if (!half) {
                float inv = 1.0f / fmaxf((float)(end - start), 1.0f);
                unsigned int ur = xt[(size_t)node * 32 + col];
                Atile[lrow * STR + col] = pack_bf2(s0 * inv + bf_lo(ur), s1 * inv + bf_hi(ur));
            }
        } else {
            float s0 = 0.f, s1 = 0.f;
            int e = start;
            while (e < end) {
                int cnt = min(64, end - e);
                int ii = e + lane; if (ii >= end) ii = end - 1;
                int idx = csr_src[ii];
                int j = 0;
                for (; j + 4 <= cnt; j += 4) {
                    int n0 = __shfl(idx, j,     64);
                    int n1 = __shfl(idx, j + 1, 64);
                    int n2 = __shfl(idx, j + 2, 64);
                    int n3 = __shfl(idx, j + 3, 64);
                    unsigned int u0 = xt[(size_t)n0 * 64 + lane];
                    unsigned int u1 = xt[(size_t)n1 * 64 + lane];
                    unsigned int u2 = xt[(size_t)n2 * 64 + lane];
                    unsigned int u3 = xt[(size_t)n3 * 64 + lane];
                    s0 += bf_lo(u0) + bf_lo(u1) + bf_lo(u2) + bf_lo(u3);
                    s1 += bf_hi(u0) + bf_hi(u1) + bf_hi(u2) + bf_hi(u3);
                }
                for (; j < cnt; ++j) {
                    int nb = __shfl(idx, j, 64);
                    unsigned int u = xt[(size_t)nb * 64 + lane];
                    s0 += bf_lo(u); s1 += bf_hi(u);
                }
                e += cnt;
            }
            float inv = 1.0f / fmaxf((float)(end - start), 1.0f);
            unsigned int ur = xt[(size_t)node * 64 + lane];
            Atile[lrow * STR + lane] = pack_bf2(s0 * inv + bf_lo(ur), s1 * inv + bf_hi(ur));
        }
    }
    __syncthreads();

    // ---- stage 2: MFMA GEMM ----
    short8 a[KC];
#pragma unroll
    for (int c = 0; c < KC; ++c)
        a[c] = *(const short8*)&Atile[(wv * 16 + r16) * STR + c * 16 + quad * 4];

    floatx4 acc[NJ];
#pragma unroll
    for (int j = 0; j < NJ; ++j)
#pragma unroll
        for (int r = 0; r < 4; ++r) acc[j][r] = 0.f;

#pragma unroll
    for (int j = 0; j < NJ; ++j)
#pragma unroll
        for (int c = 0; c < KC; ++c) {
            short8 b = *(const short8*)&Wb[(size_t)(16 * j + r16) * F_IN + 32 * c + quad * 8];
            acc[j] = __builtin_amdgcn_mfma_f32_16x16x32_bf16(a[c], b, acc[j], 0, 0, 0);
        }

    const int m0 = blockIdx.x * 64 + wv * 16;
#pragma unroll
    for (int r = 0; r < 4; ++r) {
        const int mm = m0 + quad * 4 + r;
        if (mm >= n) continue;
#pragma unroll
        for (int j = 0; j < NJ; ++j) {
            const int o = 16 * j + r16;
            float v = fmaxf(acc[j][r] + bias[o], 0.f);
            if (MODE == 0) {
                ((unsigned short*)Yb)[(size_t)mm * F_OUT + o] = f2bf_rne(v);
            } else {
                emb[(size_t)mm * 64 + o] = v;
                ((unsigned short*)Ytile)[(wv * 16 + quad * 4 + r) * 72 + o] = f2bf_rne(v);
            }
        }
    }

    if (MODE == 2) {
        // zero-fill Ytile rows for out-of-range nodes (avoid NaN garbage)
#pragma unroll
        for (int r = 0; r < 4; ++r) {
            const int mm = m0 + quad * 4 + r;
            if (mm < n) continue;
#pragma unroll
            for (int j = 0; j < NJ; ++j)
                ((unsigned short*)Ytile)[(wv * 16 + quad * 4 + r) * 72 + 16 * j + r16] = 0;
        }
        __syncthreads();

        short8 a2[2];
#pragma unroll
        for (int c = 0; c < 2; ++c)
            a2[c] = *(const short8*)&Ytile[(wv * 16 + r16) * 36 + c * 16 + quad * 4];

        floatx4 acc2[5];
#pragma unroll
        for (int j = 0; j < 5; ++j)
#pragma unroll
            for (int r = 0; r < 4; ++r) acc2[j][r] = 0.f;

#pragma unroll
        for (int j = 0; j < 5; ++j)
#pragma unroll
            for (int c = 0; c < 2; ++c) {
                short8 b = *(const short8*)&Whb[(size_t)(16 * j + r16) * 64 + 32 * c + quad * 8];
                acc2[j] = __builtin_amdgcn_mfma_f32_16x16x32_bf16(a2[c], b, acc2[j], 0, 0, 0);
            }

#pragma unroll
        for (int r = 0; r < 4; ++r) {
            const int mm = m0 + quad * 4 + r;
            if (mm >= n) continue;
#pragma unroll
            for (int j = 0; j < 5; ++j) {
                const int o = 16 * j + r16;
                float v = acc2[j][r] + hbias[o];
                if (o < 64)      nev[(size_t)mm * 64 + o] = v;
                else if (o < 74) cls[(size_t)mm * 10 + (o - 64)] = v;
            }
        }
    }
}

// ---------------- launch ----------------

extern "C" void kernel_launch(void* const* d_in, const int* in_sizes, int n_in,
                              void* d_out, int out_size, void* d_ws, size_t ws_size,
                              hipStream_t stream) {
    const float* x  = (const float*)d_in[0];
    const int*   ei = (const int*)d_in[1];
    const float* W1 = (const float*)d_in[2];
    const float* b1 = (const float*)d_in[3];
    const float* W2 = (const float*)d_in[4];
    const float* b2 = (const float*)d_in[5];
    const float* W3 = (const float*)d_in[6];
    const float* b3 = (const float*)d_in[7];
    const float* Wp = (const float*)d_in[8];
    const float* bp = (const float*)d_in[9];
    const float* Wc = (const float*)d_in[10];
    const float* bc = (const float*)d_in[11];

    const int n = in_sizes[0] / 64;   // 50000
    const int E = in_sizes[1] / 2;    // 800000
    const int* src = ei;
    const int* dst = ei + E;

    const int nScanBlocks = (n + 255) / 256;   // 196

    // workspace layout
    int* deg       = (int*)d_ws;              // n
    int* offsets   = deg + n;                 // n+1
    int* cursor    = offsets + (n + 1);       // n
    int* partial   = cursor + n;              // 256
    int* blockoff  = partial + 256;           // 256
    int* shard_cur = blockoff + 256;          // 8
    int* csr_src   = shard_cur + 8;           // E
    uintptr_t p = (uintptr_t)(csr_src + E);
    p = (p + 255) & ~(uintptr_t)255;
    int2* pairs = (int2*)p;                        // 8*REG_CAP
    unsigned int* Yb1 = (unsigned int*)(pairs + 8 * REG_CAP);  // n*64
    unsigned int* Yb2 = Yb1 + (size_t)n * 64;      // n*64
    unsigned int* xb  = Yb2 + (size_t)n * 64;      // n*32
    unsigned short* W1b = (unsigned short*)(xb + (size_t)n * 32);  // 128*64
    unsigned short* W2b = W1b + 128 * 64;          // 128*128
    unsigned short* W3b = W2b + 128 * 128;         // 64*128
    unsigned short* Whb = W3b + 64 * 128;          // 80*64
    float* hbias = (float*)(Whb + 80 * 64);        // 80

    float* out_emb = (float*)d_out;
    float* out_nev = out_emb + (size_t)n * 64;
    float* out_cls = out_nev + (size_t)n * 64;

    hipMemsetAsync(deg, 0, (size_t)n * sizeof(int), stream);

    convert_pairs_kernel<<<(n * 32 + 255) / 256, 256, 0, stream>>>(x, xb, n * 32);
    convert_pairs_kernel<<<(128 * 32 + 255) / 256, 256, 0, stream>>>(W1, (unsigned int*)W1b, 128 * 32);
    convert_pairs_kernel<<<(128 * 64 + 255) / 256, 256, 0, stream>>>(W2, (unsigned int*)W2b, 128 * 64);
    convert_pairs_kernel<<<(64 * 64 + 255) / 256, 256, 0, stream>>>(W3, (unsigned int*)W3b, 64 * 64);
    heads_pack_kernel<<<(80 * 64 + 255) / 256, 256, 0, stream>>>(Wp, bp, Wc, bc, Whb, hbias);

    init_shard_cursors_kernel<<<1, 64, 0, stream>>>(shard_cur);
    bin_edges_kernel<<<256, 256, 0, stream>>>(src, dst, shard_cur, pairs, E, 256);

    const int nSub = 64;   // 8 shards x 64 = 512 blocks
    count_deg_binned_kernel<<<8 * nSub, 256, 0, stream>>>(pairs, shard_cur, deg, nSub);
    partial_sum_kernel<<<nScanBlocks, 256, 0, stream>>>(deg, partial, n);
    scan_partials_kernel<<<1, 256, 0, stream>>>(partial, blockoff, offsets, nScanBlocks, n);
    local_scan_kernel<<<nScanBlocks, 256, 0, stream>>>(deg, blockoff, offsets, cursor, n);
    scatter_binned_kernel<<<8 * nSub, 256, 0, stream>>>(pairs, shard_cur, cursor, csr_src, nSub);

    const int gF = (n + 63) / 64;   // 782

    fused_layer_kernel<64, 128, 0><<<gF, 256, 0, stream>>>(xb, offsets, csr_src, W1b, b1,
                                                           Yb1, nullptr, nullptr, nullptr, nullptr, nullptr, n);
    fused_layer_kernel<128, 128, 0><<<gF, 256, 0, stream>>>(Yb1, offsets, csr_src, W2b, b2,
                                                            Yb2, nullptr, nullptr, nullptr, nullptr, nullptr, n);
    fused_layer_kernel<128, 64, 2><<<gF, 256, 0, stream>>>(Yb2, offsets, csr_src, W3b, b3,
                                                           nullptr, out_emb, out_nev, out_cls, Whb, hbias, n);
}

// Round 9
// 335.544 us; speedup vs baseline: 1.1236x; 1.1236x over previous
//
#include <hip/hip_runtime.h>
#include <hip/hip_bf16.h>

typedef __attribute__((ext_vector_type(8))) short short8;
typedef __attribute__((ext_vector_type(4))) float floatx4;

#define REG_CAP 106496   // per-shard pair-region capacity (~100K expected + slack)

__device__ __forceinline__ float bf_lo(unsigned int u) { return __uint_as_float(u << 16); }
__device__ __forceinline__ float bf_hi(unsigned int u) { return __uint_as_float(u & 0xffff0000u); }

__device__ __forceinline__ unsigned short f2bf_rne(float f) {
    unsigned u = __float_as_uint(f);
    unsigned rb = (u >> 16) & 1u;
    u += 0x7fffu + rb;
    return (unsigned short)(u >> 16);
}
__device__ __forceinline__ unsigned int pack_bf2(float x, float y) {
    return (unsigned int)f2bf_rne(x) | ((unsigned int)f2bf_rne(y) << 16);
}

// ---------------- one-shot convert/pack: x, W1, W2, W3, heads ----------------

__global__ __launch_bounds__(256) void convert_all_kernel(const float* __restrict__ x,
                                                          const float* __restrict__ W1,
                                                          const float* __restrict__ W2,
                                                          const float* __restrict__ W3,
                                                          const float* __restrict__ Wp, const float* __restrict__ bp,
                                                          const float* __restrict__ Wc, const float* __restrict__ bc,
                                                          unsigned int* __restrict__ xb,
                                                          unsigned int* __restrict__ W1b,
                                                          unsigned int* __restrict__ W2b,
                                                          unsigned int* __restrict__ W3b,
                                                          unsigned int* __restrict__ Whb,
                                                          float* __restrict__ hbias,
                                                          int nx) {
    int i = blockIdx.x * blockDim.x + threadIdx.x;
    const int T0 = nx;            // x pairs
    const int T1 = T0 + 4096;     // W1 128x64
    const int T2 = T1 + 8192;     // W2 128x128
    const int T3 = T2 + 4096;     // W3 64x128
    const int T4 = T3 + 2560;     // Whb 80x64
    const int T5 = T4 + 80;       // hbias
    if (i < T0) {
        float2 f = ((const float2*)x)[i];
        xb[i] = pack_bf2(f.x, f.y);
    } else if (i < T1) {
        float2 f = ((const float2*)W1)[i - T0];
        W1b[i - T0] = pack_bf2(f.x, f.y);
    } else if (i < T2) {
        float2 f = ((const float2*)W2)[i - T1];
        W2b[i - T1] = pack_bf2(f.x, f.y);
    } else if (i < T3) {
        float2 f = ((const float2*)W3)[i - T2];
        W3b[i - T2] = pack_bf2(f.x, f.y);
    } else if (i < T4) {
        int j = i - T3;
        int r = j >> 5, c = (j & 31) * 2;
        float v0 = 0.f, v1 = 0.f;
        if (r < 64)      { v0 = Wp[r * 64 + c]; v1 = Wp[r * 64 + c + 1]; }
        else if (r < 74) { v0 = Wc[(r - 64) * 64 + c]; v1 = Wc[(r - 64) * 64 + c + 1]; }
        Whb[j] = pack_bf2(v0, v1);
    } else if (i < T5) {
        int j = i - T4;
        float v = 0.f;
        if (j < 64)      v = bp[j];
        else if (j < 74) v = bc[j - 64];
        hbias[j] = v;
    }
}

// ---------------- CSR build: bin pairs by shard, then shard-local count/scatter ----------------

__global__ void init_shard_cursors_kernel(int* __restrict__ shard_cur) {
    if (threadIdx.x < 8) shard_cur[threadIdx.x] = threadIdx.x * REG_CAP;
}

__global__ __launch_bounds__(256) void bin_edges_kernel(const int* __restrict__ src,
                                                        const int* __restrict__ dst,
                                                        int* __restrict__ shard_cur,
                                                        int2* __restrict__ pairs, int E, int nBins) {
    __shared__ int cnt[8];
    __shared__ int base[8];
    const int chunk = (E + nBins - 1) / nBins;
    const int lo = blockIdx.x * chunk;
    const int hi = min(lo + chunk, E);
    if (threadIdx.x < 8) cnt[threadIdx.x] = 0;
    __syncthreads();
    for (int e = lo + threadIdx.x; e < hi; e += 256)
        atomicAdd(&cnt[(dst[e] >> 8) & 7], 1);
    __syncthreads();
    if (threadIdx.x < 8) {
        base[threadIdx.x] = atomicAdd(&shard_cur[threadIdx.x], cnt[threadIdx.x]);
        cnt[threadIdx.x] = 0;
    }
    __syncthreads();
    for (int e = lo + threadIdx.x; e < hi; e += 256) {
        int d = dst[e];
        int s = (d >> 8) & 7;
        int pos = base[s] + atomicAdd(&cnt[s], 1);
        if (pos < (s + 1) * REG_CAP) pairs[pos] = make_int2(src[e], d);
    }
}

__global__ __launch_bounds__(256) void count_deg_binned_kernel(const int2* __restrict__ pairs,
                                                               const int* __restrict__ shard_cur,
                                                               int* __restrict__ deg, int nSub) {
    const int s   = blockIdx.x & 7;
    const int sub = blockIdx.x >> 3;
    const int cnt = shard_cur[s] - s * REG_CAP;
    const int per = (cnt + nSub - 1) / nSub;
    const int lo = s * REG_CAP + sub * per;
    const int hi = min(lo + per, s * REG_CAP + cnt);
    for (int i = lo + threadIdx.x; i < hi; i += 256)
        atomicAdd(&deg[pairs[i].y], 1);
}

__global__ __launch_bounds__(256) void scatter_binned_kernel(const int2* __restrict__ pairs,
                                                             const int* __restrict__ shard_cur,
                                                             int* __restrict__ cursor,
                                                             int* __restrict__ csr_src, int nSub) {
    const int s   = blockIdx.x & 7;
    const int sub = blockIdx.x >> 3;
    const int cnt = shard_cur[s] - s * REG_CAP;
    const int per = (cnt + nSub - 1) / nSub;
    const int lo = s * REG_CAP + sub * per;
    const int hi = min(lo + per, s * REG_CAP + cnt);
    for (int i = lo + threadIdx.x; i < hi; i += 256) {
        int2 pr = pairs[i];
        int pos = atomicAdd(&cursor[pr.y], 1);
        csr_src[pos] = pr.x;
    }
}

// Two-level scan, 256 elements per block.
__global__ __launch_bounds__(256) void partial_sum_kernel(const int* __restrict__ deg,
                                                          int* __restrict__ partial, int n) {
    __shared__ int s[256];
    int t = threadIdx.x;
    int i = blockIdx.x * 256 + t;
    s[t] = (i < n) ? deg[i] : 0;
    __syncthreads();
    for (int off = 128; off > 0; off >>= 1) {
        if (t < off) s[t] += s[t + off];
        __syncthreads();
    }
    if (t == 0) partial[blockIdx.x] = s[0];
}

__global__ __launch_bounds__(256) void scan_partials_kernel(const int* __restrict__ partial,
                                                            int* __restrict__ blockoff,
                                                            int* __restrict__ offsets,
                                                            int nblocks, int n) {
    __shared__ int s[256];
    int t = threadIdx.x;
    int v = (t < nblocks) ? partial[t] : 0;
    s[t] = v;
    __syncthreads();
    for (int off = 1; off < 256; off <<= 1) {
        int u = (t >= off) ? s[t - off] : 0;
        __syncthreads();
        s[t] += u;
        __syncthreads();
    }
    if (t < nblocks) blockoff[t] = s[t] - v;
    if (t == nblocks - 1) offsets[n] = s[t];
}

__global__ __launch_bounds__(256) void local_scan_kernel(const int* __restrict__ deg,
                                                         const int* __restrict__ blockoff,
                                                         int* __restrict__ offsets,
                                                         int* __restrict__ cursor, int n) {
    __shared__ int s[256];
    int t = threadIdx.x;
    int i = blockIdx.x * 256 + t;
    int v = (i < n) ? deg[i] : 0;
    s[t] = v;
    __syncthreads();
    for (int off = 1; off < 256; off <<= 1) {
        int u = (t >= off) ? s[t - off] : 0;
        __syncthreads();
        s[t] += u;
        __syncthreads();
    }
    if (i < n) {
        int o = blockoff[blockIdx.x] + s[t] - v;
        offsets[i] = o;
        cursor[i]  = o;
    }
}

// ---------------- Aggregation (bf16, F=64): wave per node, half-wave per neighbor ----------------

__global__ __launch_bounds__(256) void agg_bf16_64_kernel(const unsigned int* __restrict__ xt,
                                                          const int* __restrict__ offsets,
                                                          const int* __restrict__ csr_src,
                                                          unsigned int* __restrict__ hb, int n) {
    const int lane = threadIdx.x & 63;
    const int node = blockIdx.x * 4 + (threadIdx.x >> 6);
    if (node >= n) return;
    const int half = lane >> 5;
    const int col  = lane & 31;
    const int start = offsets[node];
    const int end   = offsets[node + 1];

    float s0 = 0.f, s1 = 0.f;
    int e = start;
    while (e < end) {
        int cnt = min(64, end - e);
        int ii = e + lane; if (ii >= end) ii = end - 1;
        int idx = csr_src[ii];
        int j = 0;
        for (; j + 8 <= cnt; j += 8) {
            int a0 = __shfl(idx, j + 0, 64), a1 = __shfl(idx, j + 1, 64);
            int a2 = __shfl(idx, j + 2, 64), a3 = __shfl(idx, j + 3, 64);
            int a4 = __shfl(idx, j + 4, 64), a5 = __shfl(idx, j + 5, 64);
            int a6 = __shfl(idx, j + 6, 64), a7 = __shfl(idx, j + 7, 64);
            int n0 = half ? a1 : a0, n1 = half ? a3 : a2;
            int n2 = half ? a5 : a4, n3 = half ? a7 : a6;
            unsigned int u0 = xt[(size_t)n0 * 32 + col];
            unsigned int u1 = xt[(size_t)n1 * 32 + col];
            unsigned int u2 = xt[(size_t)n2 * 32 + col];
            unsigned int u3 = xt[(size_t)n3 * 32 + col];
            s0 += bf_lo(u0) + bf_lo(u1) + bf_lo(u2) + bf_lo(u3);
            s1 += bf_hi(u0) + bf_hi(u1) + bf_hi(u2) + bf_hi(u3);
        }
        for (; j + 2 <= cnt; j += 2) {
            int a0 = __shfl(idx, j, 64), a1 = __shfl(idx, j + 1, 64);
            int nb = half ? a1 : a0;
            unsigned int u = xt[(size_t)nb * 32 + col];
            s0 += bf_lo(u); s1 += bf_hi(u);
        }
        if (j < cnt) {
            int nb = __shfl(idx, j, 64);
            if (!half) {
                unsigned int u = xt[(size_t)nb * 32 + col];
                s0 += bf_lo(u); s1 += bf_hi(u);
            }
        }
        e += cnt;
    }

    s0 += __shfl(s0, lane ^ 32, 64);
    s1 += __shfl(s1, lane ^ 32, 64);

    if (!half) {
        float inv = 1.0f / fmaxf((float)(end - start), 1.0f);
        unsigned int ur = xt[(size_t)node * 32 + col];
        hb[(size_t)node * 32 + col] = pack_bf2(s0 * inv + bf_lo(ur), s1 * inv + bf_hi(ur));
    }
}

// ---------------- Aggregation (bf16, F=128): wave per node, 8 rows in flight ----------------

__global__ __launch_bounds__(256) void agg_bf16_128_kernel(const unsigned int* __restrict__ xt,
                                                           const int* __restrict__ offsets,
                                                           const int* __restrict__ csr_src,
                                                           unsigned int* __restrict__ hb, int n) {
    const int lane = threadIdx.x & 63;
    const int node = blockIdx.x * 4 + (threadIdx.x >> 6);
    if (node >= n) return;
    const int start = offsets[node];
    const int end   = offsets[node + 1];

    float s0 = 0.f, s1 = 0.f;
    int e = start;
    while (e < end) {
        int cnt = min(64, end - e);
        int ii = e + lane; if (ii >= end) ii = end - 1;
        int idx = csr_src[ii];
        int j = 0;
        for (; j + 8 <= cnt; j += 8) {
            unsigned int u[8];
#pragma unroll
            for (int q = 0; q < 8; ++q) {
                int nb = __shfl(idx, j + q, 64);
                u[q] = xt[(size_t)nb * 64 + lane];
            }
#pragma unroll
            for (int q = 0; q < 8; ++q) { s0 += bf_lo(u[q]); s1 += bf_hi(u[q]); }
        }
        for (; j < cnt; ++j) {
            int nb = __shfl(idx, j, 64);
            unsigned int u = xt[(size_t)nb * 64 + lane];
            s0 += bf_lo(u); s1 += bf_hi(u);
        }
        e += cnt;
    }

    float inv = 1.0f / fmaxf((float)(end - start), 1.0f);
    unsigned int ur = xt[(size_t)node * 64 + lane];
    hb[(size_t)node * 64 + lane] = pack_bf2(s0 * inv + bf_lo(ur), s1 * inv + bf_hi(ur));
}

// ---------------- MFMA GEMM: Y = act(H @ W^T + b), bf16 in, fp32 accum ----------------
// 256 thr = 4 waves; 64 rows/block; no LDS. A/B frags per verified 16x16x32 layout.
// MODE 0: bf16 out + relu. MODE 1: fp32 out + bf16 copy + relu (layer 3).
// MODE 2: heads — split store nev (o<64) / cls (64<=o<74), no relu.

template <int F_IN, int F_OUT, int MODE>
__global__ __launch_bounds__(256) void mfma_gemm_kernel(const unsigned short* __restrict__ Hb,
                                                        const unsigned short* __restrict__ Wb,
                                                        const float* __restrict__ bias,
                                                        unsigned short* __restrict__ Yb,
                                                        float* __restrict__ Yf,
                                                        float* __restrict__ cls, int n) {
    constexpr int KC = F_IN / 32;
    constexpr int NJ = F_OUT / 16;
    const int lane = threadIdx.x & 63;
    const int wv   = threadIdx.x >> 6;
    const int quad = lane >> 4;
    const int r16  = lane & 15;
    const int m0   = blockIdx.x * 64 + wv * 16;

    short8 a[KC];
    const int am = m0 + r16;
    if (am < n) {
#pragma unroll
        for (int c = 0; c < KC; ++c)
            a[c] = *(const short8*)&Hb[(size_t)am * F_IN + 32 * c + quad * 8];
    } else {
#pragma unroll
        for (int c = 0; c < KC; ++c)
#pragma unroll
            for (int i = 0; i < 8; ++i) a[c][i] = 0;
    }

    floatx4 acc[NJ];
#pragma unroll
    for (int j = 0; j < NJ; ++j)
#pragma unroll
        for (int r = 0; r < 4; ++r) acc[j][r] = 0.f;

#pragma unroll
    for (int j = 0; j < NJ; ++j) {
#pragma unroll
        for (int c = 0; c < KC; ++c) {
            short8 b = *(const short8*)&Wb[(size_t)(16 * j + r16) * F_IN + 32 * c + quad * 8];
            acc[j] = __builtin_amdgcn_mfma_f32_16x16x32_bf16(a[c], b, acc[j], 0, 0, 0);
        }
    }

#pragma unroll
    for (int r = 0; r < 4; ++r) {
        const int mm = m0 + quad * 4 + r;
        if (mm >= n) continue;
#pragma unroll
        for (int j = 0; j < NJ; ++j) {
            const int o = 16 * j + r16;
            float v = acc[j][r] + bias[o];
            if (MODE == 0) {
                v = fmaxf(v, 0.f);
                Yb[(size_t)mm * F_OUT + o] = f2bf_rne(v);
            } else if (MODE == 1) {
                v = fmaxf(v, 0.f);
                Yf[(size_t)mm * F_OUT + o] = v;
                Yb[(size_t)mm * F_OUT + o] = f2bf_rne(v);
            } else {
                if (o < 64)      Yf[(size_t)mm * 64 + o] = v;
                else if (o < 74) cls[(size_t)mm * 10 + (o - 64)] = v;
            }
        }
    }
}

// ---------------- launch ----------------

extern "C" void kernel_launch(void* const* d_in, const int* in_sizes, int n_in,
                              void* d_out, int out_size, void* d_ws, size_t ws_size,
                              hipStream_t stream) {
    const float* x  = (const float*)d_in[0];
    const int*   ei = (const int*)d_in[1];
    const float* W1 = (const float*)d_in[2];
    const float* b1 = (const float*)d_in[3];
    const float* W2 = (const float*)d_in[4];
    const float* b2 = (const float*)d_in[5];
    const float* W3 = (const float*)d_in[6];
    const float* b3 = (const float*)d_in[7];
    const float* Wp = (const float*)d_in[8];
    const float* bp = (const float*)d_in[9];
    const float* Wc = (const float*)d_in[10];
    const float* bc = (const float*)d_in[11];

    const int n = in_sizes[0] / 64;   // 50000
    const int E = in_sizes[1] / 2;    // 800000
    const int* src = ei;
    const int* dst = ei + E;

    const int nScanBlocks = (n + 255) / 256;   // 196

    // workspace layout
    int* deg       = (int*)d_ws;              // n
    int* offsets   = deg + n;                 // n+1
    int* cursor    = offsets + (n + 1);       // n
    int* partial   = cursor + n;              // 256
    int* blockoff  = partial + 256;           // 256
    int* shard_cur = blockoff + 256;          // 8
    int* csr_src   = shard_cur + 8;           // E
    uintptr_t p = (uintptr_t)(csr_src + E);
    p = (p + 255) & ~(uintptr_t)255;
    int2* pairs = (int2*)p;                        // 8*REG_CAP
    unsigned int* Hb  = (unsigned int*)(pairs + 8 * REG_CAP);  // n*64
    unsigned int* Yb  = Hb + (size_t)n * 64;       // n*64
    unsigned int* xb  = Yb + (size_t)n * 64;       // n*32
    unsigned int* Xb3 = xb + (size_t)n * 32;       // n*32 (emb bf16)
    unsigned int* W1b = Xb3 + (size_t)n * 32;      // 4096 uints
    unsigned int* W2b = W1b + 4096;                // 8192
    unsigned int* W3b = W2b + 8192;                // 4096
    unsigned int* Whb = W3b + 4096;                // 2560
    float* hbias = (float*)(Whb + 2560);           // 80

    float* out_emb = (float*)d_out;
    float* out_nev = out_emb + (size_t)n * 64;
    float* out_cls = out_nev + (size_t)n * 64;

    hipMemsetAsync(deg, 0, (size_t)n * sizeof(int), stream);

    const int convTotal = n * 32 + 4096 + 8192 + 4096 + 2560 + 80;
    convert_all_kernel<<<(convTotal + 255) / 256, 256, 0, stream>>>(
        x, W1, W2, W3, Wp, bp, Wc, bc, xb, W1b, W2b, W3b, Whb, hbias, n * 32);

    init_shard_cursors_kernel<<<1, 64, 0, stream>>>(shard_cur);
    bin_edges_kernel<<<256, 256, 0, stream>>>(src, dst, shard_cur, pairs, E, 256);

    const int nSub = 64;   // 8 shards x 64 = 512 blocks
    count_deg_binned_kernel<<<8 * nSub, 256, 0, stream>>>(pairs, shard_cur, deg, nSub);
    partial_sum_kernel<<<nScanBlocks, 256, 0, stream>>>(deg, partial, n);
    scan_partials_kernel<<<1, 256, 0, stream>>>(partial, blockoff, offsets, nScanBlocks, n);
    local_scan_kernel<<<nScanBlocks, 256, 0, stream>>>(deg, blockoff, offsets, cursor, n);
    scatter_binned_kernel<<<8 * nSub, 256, 0, stream>>>(pairs, shard_cur, cursor, csr_src, nSub);

    const int gAgg = (n + 3) / 4;    // 12500
    const int gMf  = (n + 63) / 64;  // 782

    agg_bf16_64_kernel<<<gAgg, 256, 0, stream>>>(xb, offsets, csr_src, Hb, n);
    mfma_gemm_kernel<64, 128, 0><<<gMf, 256, 0, stream>>>((const unsigned short*)Hb, (const unsigned short*)W1b, b1,
                                                          (unsigned short*)Yb, nullptr, nullptr, n);

    agg_bf16_128_kernel<<<gAgg, 256, 0, stream>>>(Yb, offsets, csr_src, Hb, n);
    mfma_gemm_kernel<128, 128, 0><<<gMf, 256, 0, stream>>>((const unsigned short*)Hb, (const unsigned short*)W2b, b2,
                                                           (unsigned short*)Yb, nullptr, nullptr, n);

    agg_bf16_128_kernel<<<gAgg, 256, 0, stream>>>(Yb, offsets, csr_src, Hb, n);
    mfma_gemm_kernel<128, 64, 1><<<gMf, 256, 0, stream>>>((const unsigned short*)Hb, (const unsigned short*)W3b, b3,
                                                          (unsigned short*)Xb3, out_emb, nullptr, n);

    mfma_gemm_kernel<64, 80, 2><<<gMf, 256, 0, stream>>>((const unsigned short*)Xb3, (const unsigned short*)Whb, hbias,
                                                         nullptr, out_nev, out_cls, n);
}